// Round 1
// 351.025 us; speedup vs baseline: 1.3272x; 1.3272x over previous
//
#include <hip/hip_runtime.h>

typedef __attribute__((ext_vector_type(8))) short bf16x8;
typedef __attribute__((ext_vector_type(4))) float f32x4;
typedef __attribute__((ext_vector_type(8))) unsigned short ushort8;
typedef __attribute__((ext_vector_type(4))) unsigned short ushort4v;
typedef __attribute__((ext_vector_type(4))) float float4v;
typedef __attribute__((ext_vector_type(2))) unsigned int uint2v;

#define TGT 256
#define BSZ 64
#define EMB 1024
#define NH 16
#define HD 64
#define PP 16

__device__ __forceinline__ float b2f(unsigned short u) {
  return __builtin_bit_cast(float, ((unsigned int)u) << 16);
}
__device__ __forceinline__ unsigned short f2b(float f) {
  unsigned int u = __builtin_bit_cast(unsigned int, f);
  u += 0x7fffu + ((u >> 16) & 1u);  // RNE; no NaNs in this workload
  return (unsigned short)(u >> 16);
}
__device__ __forceinline__ unsigned int pack2(float lo, float hi) {
  return (unsigned int)f2b(lo) | ((unsigned int)f2b(hi) << 16);
}
__device__ __forceinline__ f32x4 mfma16(bf16x8 a, bf16x8 b, f32x4 c) {
  return __builtin_amdgcn_mfma_f32_16x16x32_bf16(a, b, c, 0, 0, 0);
}
// async global->LDS, 16B per lane; LDS dest is wave-uniform base + lane*16
__device__ __forceinline__ void gl_lds16(const unsigned short* g, unsigned short* l) {
  __builtin_amdgcn_global_load_lds(
      (const __attribute__((address_space(1))) unsigned int*)g,
      (__attribute__((address_space(3))) unsigned int*)l, 16, 0, 0);
}

// ---------------------------------------------------------------------------
// Gate: g1[b] = softmax((feat[b]@gw.T + gb + noise[b]) / 3)[1]
// ---------------------------------------------------------------------------
__global__ __launch_bounds__(64) void gate_kernel(
    const float* __restrict__ feat, const float* __restrict__ gw,
    const float* __restrict__ gb, const float* __restrict__ noise,
    float* __restrict__ g1) {
  const int b = blockIdx.x, lane = threadIdx.x;
  float a0 = 0.f, a1 = 0.f;
  for (int i = lane; i < 512; i += 64) {
    float f = feat[b * 512 + i];
    a0 += f * gw[i];
    a1 += f * gw[512 + i];
  }
#pragma unroll
  for (int off = 32; off >= 1; off >>= 1) {
    a0 += __shfl_xor(a0, off);
    a1 += __shfl_xor(a1, off);
  }
  if (lane == 0) {
    float l0 = (a0 + gb[0] + noise[b * 2 + 0]) * (1.0f / 3.0f);
    float l1 = (a1 + gb[1] + noise[b * 2 + 1]) * (1.0f / 3.0f);
    float mm = fmaxf(l0, l1);
    float e0 = __expf(l0 - mm), e1 = __expf(l1 - mm);
    g1[b] = e1 / (e0 + e1);
  }
}

// ---------------------------------------------------------------------------
// f32 -> bf16 cast, 8 elems/thread, grid-stride
// ---------------------------------------------------------------------------
__global__ __launch_bounds__(256) void cast_bf16_kernel(
    const float* __restrict__ in, unsigned short* __restrict__ out, int n8) {
  int i = blockIdx.x * blockDim.x + threadIdx.x;
  const int stride = gridDim.x * blockDim.x;
  for (; i < n8; i += stride) {
    const float4v* p = (const float4v*)(in + (size_t)i * 8);
    float4v v0 = p[0], v1 = p[1];
    ushort8 o = {f2b(v0[0]), f2b(v0[1]), f2b(v0[2]), f2b(v0[3]),
                 f2b(v1[0]), f2b(v1[1]), f2b(v1[2]), f2b(v1[3])};
    *(ushort8*)(out + (size_t)i * 8) = o;
  }
}

// ---------------------------------------------------------------------------
// bf16 GEMM: C[16384,1024] = A[16384,1024] @ W[1024,1024]^T + bias
// m97 structure: 128x128 tile, BK=64, 4 waves (2x2 of 64x64), both operands
// staged via global_load_lds dwordx4 into linear LDS, 2-barrier loop.
// XCD-chunked block swizzle: nwg=1024 (8 n-tiles x 128 m-tiles); each XCD
// gets a contiguous logical chunk so the 8 n-blocks sharing an A row-panel
// land on one XCD's L2 (A fetched once from HBM).
// QSCALE folds attention 1/sqrt(d) into the q-projection output (free).
// ---------------------------------------------------------------------------
template <int OUT_F32, int QSCALE>
__global__ __launch_bounds__(256) void gemm_bf16_kernel(
    const unsigned short* __restrict__ A, const unsigned short* __restrict__ W,
    const float* __restrict__ bias, void* __restrict__ Cv) {
  constexpr int K = 1024, N = 1024, BK = 64;
  __shared__ __attribute__((aligned(16))) unsigned short As[128 * BK];
  __shared__ __attribute__((aligned(16))) unsigned short Bs[128 * BK];
  const int tid = threadIdx.x;
  const int wv = tid >> 6, lane = tid & 63;
  const int l15 = lane & 15, kg = lane >> 4;
  // bijective XCD swizzle (nwg % 8 == 0)
  const int bid = blockIdx.x;
  const int cpx = gridDim.x >> 3;
  const int wg = (bid & 7) * cpx + (bid >> 3);
  const int m0 = (wg >> 3) * 128, n0 = (wg & 7) * 128;
  const int wm = (wv >> 1) * 64, wn = (wv & 1) * 64;
  // staging geometry: chunk c = wv*4+it covers 8 rows (1024B); lane writes
  // row c*8 + (lane>>3), cols (lane&7)*8 .. +8
  const int srow = lane >> 3, scol = (lane & 7) * 8;
  const unsigned short* Ab = A + (size_t)(m0 + wv * 32 + srow) * K + scol;
  const unsigned short* Wb = W + (size_t)(n0 + wv * 32 + srow) * K + scol;

  f32x4 acc[4][4];
#pragma unroll
  for (int i = 0; i < 4; ++i)
#pragma unroll
    for (int j = 0; j < 4; ++j) acc[i][j] = (f32x4){0.f, 0.f, 0.f, 0.f};

  for (int k0 = 0; k0 < K; k0 += BK) {
#pragma unroll
    for (int it = 0; it < 4; ++it) {
      gl_lds16(Ab + (size_t)(it * 8) * K + k0, &As[(wv * 4 + it) * 512]);
      gl_lds16(Wb + (size_t)(it * 8) * K + k0, &Bs[(wv * 4 + it) * 512]);
    }
    __syncthreads();  // compiler drains vmcnt before s_barrier
    bf16x8 af[2][4], bf[2][4];
#pragma unroll
    for (int kk = 0; kk < 2; ++kk)
#pragma unroll
      for (int mi = 0; mi < 4; ++mi)
        af[kk][mi] = *(const bf16x8*)&As[(wm + mi * 16 + l15) * BK + kk * 32 + kg * 8];
#pragma unroll
    for (int kk = 0; kk < 2; ++kk)
#pragma unroll
      for (int ni = 0; ni < 4; ++ni)
        bf[kk][ni] = *(const bf16x8*)&Bs[(wn + ni * 16 + l15) * BK + kk * 32 + kg * 8];
#pragma unroll
    for (int mi = 0; mi < 4; ++mi)
#pragma unroll
      for (int ni = 0; ni < 4; ++ni) {
        acc[mi][ni] = mfma16(af[0][mi], bf[0][ni], acc[mi][ni]);
        acc[mi][ni] = mfma16(af[1][mi], bf[1][ni], acc[mi][ni]);
      }
    __syncthreads();
  }

#pragma unroll
  for (int mi = 0; mi < 4; ++mi) {
#pragma unroll
    for (int ni = 0; ni < 4; ++ni) {
      int col = n0 + wn + ni * 16 + l15;
      float bcol = bias[col];
#pragma unroll
      for (int r = 0; r < 4; ++r) {
        int row = m0 + wm + mi * 16 + kg * 4 + r;
        float v = acc[mi][ni][r] + bcol;
        if constexpr (QSCALE) v *= 0.125f;
        if constexpr (OUT_F32)
          ((float*)Cv)[(size_t)row * N + col] = v;
        else
          ((unsigned short*)Cv)[(size_t)row * N + col] = f2b(v);
      }
    }
  }
}

// ---------------------------------------------------------------------------
// MFMA attention per (b,h). 8 waves x 32 t-rows (2 strips of 16).
// S^T = K·Q^T via mfma (lane: t=l15, s=g*4+r); online softmax in f32;
// P^T staged through a PRIVATE per-wave LDS tile (no shfl routing, no asm);
// O^T = V^T·P^T via mfma, V^T stored chunk-XOR-swizzled in LDS.
// Prefix (P=16, zero-padded to 32) reuses the same P-tile path.
// combined = attn + g1[t>>2]*bw[b]*attn_pre   (uses g0+g1==1).
// Q is pre-scaled by 0.125 in the q-projection GEMM.
// ---------------------------------------------------------------------------
__global__ __launch_bounds__(512) void attn_kernel(
    const unsigned short* __restrict__ qb, const unsigned short* __restrict__ kb,
    const unsigned short* __restrict__ vb, const float* __restrict__ prefix,
    const float* __restrict__ bw, const float* __restrict__ g1,
    unsigned short* __restrict__ comb) {
  const int b = blockIdx.x, h = blockIdx.y;
  __shared__ __attribute__((aligned(16))) unsigned short Kl[256][64];    // 32 KB, chunk-XOR
  __shared__ __attribute__((aligned(16))) unsigned short Vt[64 * 256];   // 32 KB, V^T chunk-XOR
  __shared__ __attribute__((aligned(16))) unsigned short PKl[16][64];    // 2 KB, chunk-XOR
  __shared__ __attribute__((aligned(16))) unsigned short PVt[64][32];    // 4 KB
  __shared__ __attribute__((aligned(16))) unsigned short Plds[8][16][40];// 10 KB, per-wave P
  unsigned short* Cb = &Kl[0][0];  // output bounce overlays Kl (exactly 16384 ushorts)
  const int tid = threadIdx.x;

  // ---- staging ----
#pragma unroll
  for (int it = 0; it < 4; ++it) {
    int cid = tid + it * 512;
    int j = cid >> 3, c = cid & 7;  // j = s row, c = d-chunk
    size_t gro = (size_t)(j * BSZ + b) * EMB + h * HD + c * 8;
    *(ushort8*)&Kl[j][((c ^ (j & 7)) << 3)] = *(const ushort8*)(kb + gro);
    ushort8 vv = *(const ushort8*)(vb + gro);
#pragma unroll
    for (int i = 0; i < 8; ++i)  // V^T: element (d=c*8+i, s=j) at [d][((s>>3)^(d&7))<<3 | (s&7)]
      Vt[(c * 8 + i) * 256 + (((j >> 3) ^ i) << 3) + (j & 7)] = vv[i];
  }
  if (tid < 256) {
    int arr = tid >> 7, cid = tid & 127;
    int sp = cid >> 3, c = cid & 7;
    const float* src = prefix + ((size_t)(b * 2 + arr) * PP + sp) * EMB + h * HD + c * 8;
    float4v v0 = *(const float4v*)src;
    float4v v1 = *(const float4v*)(src + 4);
    if (arr == 0) {
      ushort8 o = {f2b(v0[0]), f2b(v0[1]), f2b(v0[2]), f2b(v0[3]),
                   f2b(v1[0]), f2b(v1[1]), f2b(v1[2]), f2b(v1[3])};
      *(ushort8*)&PKl[sp][((c ^ (sp & 7)) << 3)] = o;
    } else {
#pragma unroll
      for (int i = 0; i < 8; ++i)
        PVt[c * 8 + i][sp] = f2b(i < 4 ? v0[i] : v1[i - 4]);
    }
  } else if (tid < 384) {
    int cid = tid - 256;
    *(ushort8*)&PVt[cid >> 1][16 + (cid & 1) * 8] = (ushort8){0, 0, 0, 0, 0, 0, 0, 0};
  }
  __syncthreads();

  const int wv = tid >> 6, lane = tid & 63;
  const int l15 = lane & 15, g = lane >> 4;
  const int swl = l15 & 7;
  const float bwb = bw[b];
  unsigned short(&Pw)[16][40] = Plds[wv];
  f32x4 Oacc[2][4];

#pragma unroll
  for (int sI = 0; sI < 2; ++sI) {
    const int tg = wv * 32 + sI * 16 + l15;
    const size_t qoff = (size_t)(tg * BSZ + b) * EMB + h * HD;
    bf16x8 qf0 = *(const bf16x8*)(qb + qoff + g * 8);
    bf16x8 qf1 = *(const bf16x8*)(qb + qoff + 32 + g * 8);
    f32x4 O[4];
#pragma unroll
    for (int dt = 0; dt < 4; ++dt) O[dt] = (f32x4){0.f, 0.f, 0.f, 0.f};
    float m = -3.0e38f, l = 0.f;

#pragma unroll
    for (int ch = 0; ch < 8; ++ch) {  // 32 s per chunk
      const int rA = ch * 32 + l15, rB = rA + 16;
      bf16x8 ka0 = *(const bf16x8*)&Kl[rA][((g ^ swl) << 3)];
      bf16x8 ka1 = *(const bf16x8*)&Kl[rA][(((4 + g) ^ swl) << 3)];
      bf16x8 kb0 = *(const bf16x8*)&Kl[rB][((g ^ swl) << 3)];
      bf16x8 kb1 = *(const bf16x8*)&Kl[rB][(((4 + g) ^ swl) << 3)];
      f32x4 sa = (f32x4){0.f, 0.f, 0.f, 0.f}, sb = sa;
      sa = mfma16(ka0, qf0, sa);
      sa = mfma16(ka1, qf1, sa);
      sb = mfma16(kb0, qf0, sb);
      sb = mfma16(kb1, qf1, sb);
      float mx = fmaxf(fmaxf(fmaxf(sa[0], sa[1]), fmaxf(sa[2], sa[3])),
                       fmaxf(fmaxf(sb[0], sb[1]), fmaxf(sb[2], sb[3])));
      mx = fmaxf(mx, __shfl_xor(mx, 16));
      mx = fmaxf(mx, __shfl_xor(mx, 32));
      float mn = fmaxf(m, mx);
      float f = __expf(m - mn);
      m = mn;
      float pA[4], pB[4];
#pragma unroll
      for (int r = 0; r < 4; ++r) {
        pA[r] = __expf(sa[r] - m);
        pB[r] = __expf(sb[r] - m);
      }
      uint2v wa = {pack2(pA[0], pA[1]), pack2(pA[2], pA[3])};
      uint2v wb2 = {pack2(pB[0], pB[1]), pack2(pB[2], pB[3])};
      *(uint2v*)&Pw[l15][g * 4] = wa;
      *(uint2v*)&Pw[l15][16 + g * 4] = wb2;
      float sloc = b2f((unsigned short)(wa[0] & 0xffff)) + b2f((unsigned short)(wa[0] >> 16)) +
                   b2f((unsigned short)(wa[1] & 0xffff)) + b2f((unsigned short)(wa[1] >> 16)) +
                   b2f((unsigned short)(wb2[0] & 0xffff)) + b2f((unsigned short)(wb2[0] >> 16)) +
                   b2f((unsigned short)(wb2[1] & 0xffff)) + b2f((unsigned short)(wb2[1] >> 16));
      l = l * f + sloc;
#pragma unroll
      for (int dt = 0; dt < 4; ++dt)
#pragma unroll
        for (int r = 0; r < 4; ++r) O[dt][r] *= f;
      bf16x8 pf = *(const bf16x8*)&Pw[l15][g * 8];
#pragma unroll
      for (int dt = 0; dt < 4; ++dt) {
        const int drow = dt * 16 + l15;
        bf16x8 vf = *(const bf16x8*)&Vt[drow * 256 + (((ch * 4 + g) ^ (drow & 7)) << 3)];
        O[dt] = mfma16(vf, pf, O[dt]);
      }
    }

    float lf = l;
    lf += __shfl_xor(lf, 16);
    lf += __shfl_xor(lf, 32);
    float inv = 1.0f / lf;
#pragma unroll
    for (int dt = 0; dt < 4; ++dt)
#pragma unroll
      for (int r = 0; r < 4; ++r) O[dt][r] *= inv;

    bf16x8 pk0 = *(const bf16x8*)&PKl[l15][((g ^ swl) << 3)];
    bf16x8 pk1 = *(const bf16x8*)&PKl[l15][(((4 + g) ^ swl) << 3)];
    f32x4 sp4 = (f32x4){0.f, 0.f, 0.f, 0.f};
    sp4 = mfma16(pk0, qf0, sp4);
    sp4 = mfma16(pk1, qf1, sp4);
    float pm = fmaxf(fmaxf(sp4[0], sp4[1]), fmaxf(sp4[2], sp4[3]));
    pm = fmaxf(pm, __shfl_xor(pm, 16));
    pm = fmaxf(pm, __shfl_xor(pm, 32));
    float pe[4], pl = 0.f;
#pragma unroll
    for (int r = 0; r < 4; ++r) {
      pe[r] = __expf(sp4[r] - pm);
      pl += pe[r];
    }
    pl += __shfl_xor(pl, 16);
    pl += __shfl_xor(pl, 32);
    float cpre = g1[tg >> 2] * bwb / pl;
#pragma unroll
    for (int r = 0; r < 4; ++r) pe[r] *= cpre;
    *(uint2v*)&Pw[l15][g * 4] = (uint2v){pack2(pe[0], pe[1]), pack2(pe[2], pe[3])};
    *(uint2v*)&Pw[l15][16 + g * 4] = (uint2v){0u, 0u};
    bf16x8 ppf = *(const bf16x8*)&Pw[l15][g * 8];
#pragma unroll
    for (int dt = 0; dt < 4; ++dt) {
      bf16x8 pvf = *(const bf16x8*)&PVt[dt * 16 + l15][g * 8];
      O[dt] = mfma16(pvf, ppf, O[dt]);
    }
#pragma unroll
    for (int dt = 0; dt < 4; ++dt) Oacc[sI][dt] = O[dt];
  }

  __syncthreads();  // all waves done reading Kl before bounce overlays it
#pragma unroll
  for (int sI = 0; sI < 2; ++sI) {
    int t = wv * 32 + sI * 16 + l15;
#pragma unroll
    for (int dt = 0; dt < 4; ++dt) {
#pragma unroll
      for (int u = 0; u < 2; ++u) {
        unsigned int pw = pack2(Oacc[sI][dt][2 * u], Oacc[sI][dt][2 * u + 1]);
        int d = dt * 16 + g * 4 + 2 * u;
        *(unsigned int*)&Cb[t * 64 + (((d >> 3) ^ (t & 7)) << 3) + (d & 7)] = pw;
      }
    }
  }
  __syncthreads();
#pragma unroll
  for (int it = 0; it < 4; ++it) {
    int cid = tid + it * 512;
    int j = cid >> 3, c = cid & 7;
    ushort8 row = *(const ushort8*)&Cb[j * 64 + ((c ^ (j & 7)) << 3)];
    *(ushort8*)(comb + (size_t)(j * BSZ + b) * EMB + h * HD + c * 8) = row;
  }
}

// ---------------------------------------------------------------------------
extern "C" void kernel_launch(void* const* d_in, const int* in_sizes, int n_in,
                              void* d_out, int out_size, void* d_ws, size_t ws_size,
                              hipStream_t stream) {
  const float* query = (const float*)d_in[1];
  const float* key = (const float*)d_in[2];
  const float* value = (const float*)d_in[3];
  const float* prefix = (const float*)d_in[4];
  const float* bw = (const float*)d_in[5];
  const float* feat = (const float*)d_in[6];
  const float* noise = (const float*)d_in[7];
  const float* ipw = (const float*)d_in[8];
  const float* ipb = (const float*)d_in[9];
  const float* outw = (const float*)d_in[10];
  const float* outb = (const float*)d_in[11];
  const float* gw = (const float*)d_in[12];
  const float* gb = (const float*)d_in[13];
  float* out = (float*)d_out;

  char* ws = (char*)d_ws;
  const size_t MATB = (size_t)16384 * 1024;  // elements per [16384,1024] matrix
  unsigned short* qb = (unsigned short*)ws;
  unsigned short* kb = qb + MATB;
  unsigned short* vb = kb + MATB;
  unsigned short* cb = vb + MATB;            // attn output; also A-cast scratch
  unsigned short* wip = cb + MATB;           // bf16 in_proj_w [3072,1024]
  unsigned short* wo = wip + (size_t)3072 * 1024;  // bf16 out_w [1024,1024]
  float* g1 = (float*)(wo + (size_t)1024 * 1024);

  gate_kernel<<<64, 64, 0, stream>>>(feat, gw, gb, noise, g1);

  // one-time weight casts (cheap: 12.6 MB + 4.2 MB read)
  cast_bf16_kernel<<<1536, 256, 0, stream>>>(ipw, wip, 3072 * 1024 / 8);
  cast_bf16_kernel<<<512, 256, 0, stream>>>(outw, wo, 1024 * 1024 / 8);

  const int N8 = (int)(MATB / 8);
  // q projection (cb used as bf16-A scratch before attn overwrites it)
  cast_bf16_kernel<<<2048, 256, 0, stream>>>(query, cb, N8);
  gemm_bf16_kernel<0, 1><<<1024, 256, 0, stream>>>(cb, wip, ipb, qb);
  // k projection
  cast_bf16_kernel<<<2048, 256, 0, stream>>>(key, cb, N8);
  gemm_bf16_kernel<0, 0><<<1024, 256, 0, stream>>>(cb, wip + (size_t)1024 * 1024, ipb + 1024, kb);
  // v projection
  cast_bf16_kernel<<<2048, 256, 0, stream>>>(value, cb, N8);
  gemm_bf16_kernel<0, 0><<<1024, 256, 0, stream>>>(cb, wip + (size_t)2048 * 1024, ipb + 2048, vb);

  attn_kernel<<<dim3(64, 16), 512, 0, stream>>>(qb, kb, vb, prefix, bw, g1, cb);

  gemm_bf16_kernel<1, 0><<<1024, 256, 0, stream>>>(cb, wo, outb, out);
}

// Round 2
// 295.283 us; speedup vs baseline: 1.5777x; 1.1888x over previous
//
#include <hip/hip_runtime.h>

typedef __attribute__((ext_vector_type(8))) short bf16x8;
typedef __attribute__((ext_vector_type(4))) float f32x4;
typedef __attribute__((ext_vector_type(8))) unsigned short ushort8;
typedef __attribute__((ext_vector_type(4))) unsigned short ushort4v;
typedef __attribute__((ext_vector_type(4))) float float4v;
typedef __attribute__((ext_vector_type(2))) unsigned int uint2v;

#define TGT 256
#define BSZ 64
#define EMB 1024
#define NH 16
#define HD 64
#define PP 16

__device__ __forceinline__ float b2f(unsigned short u) {
  return __builtin_bit_cast(float, ((unsigned int)u) << 16);
}
__device__ __forceinline__ unsigned short f2b(float f) {
  unsigned int u = __builtin_bit_cast(unsigned int, f);
  u += 0x7fffu + ((u >> 16) & 1u);  // RNE; no NaNs in this workload
  return (unsigned short)(u >> 16);
}
__device__ __forceinline__ unsigned int pack2(float lo, float hi) {
  return (unsigned int)f2b(lo) | ((unsigned int)f2b(hi) << 16);
}
__device__ __forceinline__ f32x4 mfma16(bf16x8 a, bf16x8 b, f32x4 c) {
  return __builtin_amdgcn_mfma_f32_16x16x32_bf16(a, b, c, 0, 0, 0);
}
// async global->LDS, 16B per lane; LDS dest is wave-uniform base + lane*16
__device__ __forceinline__ void gl_lds16(const unsigned short* g, unsigned short* l) {
  __builtin_amdgcn_global_load_lds(
      (const __attribute__((address_space(1))) unsigned int*)g,
      (__attribute__((address_space(3))) unsigned int*)l, 16, 0, 0);
}

// ---------------------------------------------------------------------------
// Gate: g1[b] = softmax((feat[b]@gw.T + gb + noise[b]) / 3)[1]
// ---------------------------------------------------------------------------
__global__ __launch_bounds__(64) void gate_kernel(
    const float* __restrict__ feat, const float* __restrict__ gw,
    const float* __restrict__ gb, const float* __restrict__ noise,
    float* __restrict__ g1) {
  const int b = blockIdx.x, lane = threadIdx.x;
  float a0 = 0.f, a1 = 0.f;
  for (int i = lane; i < 512; i += 64) {
    float f = feat[b * 512 + i];
    a0 += f * gw[i];
    a1 += f * gw[512 + i];
  }
#pragma unroll
  for (int off = 32; off >= 1; off >>= 1) {
    a0 += __shfl_xor(a0, off);
    a1 += __shfl_xor(a1, off);
  }
  if (lane == 0) {
    float l0 = (a0 + gb[0] + noise[b * 2 + 0]) * (1.0f / 3.0f);
    float l1 = (a1 + gb[1] + noise[b * 2 + 1]) * (1.0f / 3.0f);
    float mm = fmaxf(l0, l1);
    float e0 = __expf(l0 - mm), e1 = __expf(l1 - mm);
    g1[b] = e1 / (e0 + e1);
  }
}

// ---------------------------------------------------------------------------
// f32 -> bf16 cast, 8 elems/thread, grid-stride
// ---------------------------------------------------------------------------
__global__ __launch_bounds__(256) void cast_bf16_kernel(
    const float* __restrict__ in, unsigned short* __restrict__ out, int n8) {
  int i = blockIdx.x * blockDim.x + threadIdx.x;
  const int stride = gridDim.x * blockDim.x;
  for (; i < n8; i += stride) {
    const float4v* p = (const float4v*)(in + (size_t)i * 8);
    float4v v0 = p[0], v1 = p[1];
    ushort8 o = {f2b(v0[0]), f2b(v0[1]), f2b(v0[2]), f2b(v0[3]),
                 f2b(v1[0]), f2b(v1[1]), f2b(v1[2]), f2b(v1[3])};
    *(ushort8*)(out + (size_t)i * 8) = o;
  }
}

// ---------------------------------------------------------------------------
// bf16 GEMM: C[16384,1024] = A[16384,1024] @ W[1024,1024]^T + bias
// 256x256 tile, 8 waves (2Mx4N, each owns 128x64), BK=32, K=1024 -> 32 steps.
// Phase-interleaved schedule with COUNTED vmcnt (T3+T4), LDS XOR swizzle (T2),
// setprio around MFMA clusters (T5), XCD-chunked block swizzle (T1).
//
// LDS: ring of 4 K-step slots per operand (4 x 16KB A + 4 x 16KB B = 128 KB).
// Prefetch lead = 3 steps: during step s we issue gl_lds for step s+3 into
// slot (s+3)&3 == (s-1)&3 -- never the slot being read (s&3), and the slot
// being overwritten was last read before the step-(s-1) end barrier. At each
// step end: s_waitcnt vmcnt(8) (steps s+2,s+3 in flight = 8 loads, never 0)
// then raw s_barrier. Each step = 2 phases:
//   {ds_read frags | issue 2 gl_lds -> barrier -> setprio(1) 16 MFMA setprio(0) -> barrier}
//
// Swizzle: element (r,c) of a [256][32]-bf16 slot stored at ushort index
// r*32 + (c ^ (((r>>1)&3)<<3)). Banks depend on {r[0], colbyte[5:2]}; the XOR
// gives 16 lanes -> 2-way bank groups (free, m136). gl_lds dest stays linear;
// the global SOURCE address is pre-swizzled (both-sides-or-neither rule).
// ---------------------------------------------------------------------------
#define STAGE_A(s)                                       \
  {                                                      \
    int k0s = (s) * 32;                                  \
    unsigned short* d = &As[(s) & 3][wl];                \
    gl_lds16(a0p + k0s, d);                              \
    gl_lds16(a1p + k0s, d + 4096);                       \
  }
#define STAGE_B(s)                                       \
  {                                                      \
    int k0s = (s) * 32;                                  \
    unsigned short* d = &Bs[(s) & 3][wl];                \
    gl_lds16(b0p + k0s, d);                              \
    gl_lds16(b1p + k0s, d + 4096);                       \
  }
#define GEMM_STEP(s, DO_STAGE)                                        \
  {                                                                   \
    const unsigned short* Ab = &As[(s) & 3][0];                       \
    const unsigned short* Bb = &Bs[(s) & 3][0];                       \
    bf16x8 af[8], bfr[4];                                             \
    _Pragma("unroll") for (int mi = 0; mi < 8; ++mi)                  \
        af[mi] = *(const bf16x8*)&Ab[aoff + mi * 512];                \
    _Pragma("unroll") for (int ni = 0; ni < 2; ++ni)                  \
        bfr[ni] = *(const bf16x8*)&Bb[boff + ni * 512];               \
    if (DO_STAGE) STAGE_A((s) + 3);                                   \
    __builtin_amdgcn_s_barrier();                                     \
    __builtin_amdgcn_s_setprio(1);                                    \
    _Pragma("unroll") for (int mi = 0; mi < 8; ++mi) {                \
      acc[mi][0] = mfma16(af[mi], bfr[0], acc[mi][0]);                \
      acc[mi][1] = mfma16(af[mi], bfr[1], acc[mi][1]);                \
    }                                                                 \
    __builtin_amdgcn_s_setprio(0);                                    \
    __builtin_amdgcn_s_barrier();                                     \
    _Pragma("unroll") for (int ni = 2; ni < 4; ++ni)                  \
        bfr[ni] = *(const bf16x8*)&Bb[boff + ni * 512];               \
    if (DO_STAGE) STAGE_B((s) + 3);                                   \
    __builtin_amdgcn_s_barrier();                                     \
    __builtin_amdgcn_s_setprio(1);                                    \
    _Pragma("unroll") for (int mi = 0; mi < 8; ++mi) {                \
      acc[mi][2] = mfma16(af[mi], bfr[2], acc[mi][2]);                \
      acc[mi][3] = mfma16(af[mi], bfr[3], acc[mi][3]);                \
    }                                                                 \
    __builtin_amdgcn_s_setprio(0);                                    \
  }
#define STEP_WAIT(cntstr)                                \
  asm volatile("s_waitcnt " cntstr ::: "memory");        \
  __builtin_amdgcn_sched_barrier(0);                     \
  __builtin_amdgcn_s_barrier();

template <int OUT_F32, int QSCALE>
__global__ __launch_bounds__(512, 2) void gemm256_kernel(
    const unsigned short* __restrict__ A, const unsigned short* __restrict__ W,
    const float* __restrict__ bias, void* __restrict__ Cv) {
  constexpr int K = 1024, N = 1024;
  __shared__ __attribute__((aligned(16))) unsigned short As[4][8192];  // 64 KB
  __shared__ __attribute__((aligned(16))) unsigned short Bs[4][8192];  // 64 KB
  const int tid = threadIdx.x;
  const int wv = tid >> 6, lane = tid & 63;
  const int l15 = lane & 15, kg = lane >> 4;
  // XCD-chunked swizzle (nwg = 256, 32 logical wgs per XCD)
  const int bid = blockIdx.x;
  const int cpx = gridDim.x >> 3;
  const int wg = (bid & 7) * cpx + (bid >> 3);
  const int m0 = (wg >> 2) * 256, n0 = (wg & 3) * 256;
  const int wmL = (wv >> 2) * 128, wnL = (wv & 3) * 64;

  // staging: each wave stages 16 rows per half (2 halves of 128 rows / issue);
  // lane covers row sr, 8 ushorts at swizzled source column
  const int sr = wv * 16 + (lane >> 2);  // row within 128-row half
  const int sc = ((lane & 3) * 8) ^ (((sr >> 1) & 3) << 3);  // pre-swizzled src col
  const unsigned short* a0p = A + (size_t)(m0 + sr) * K + sc;
  const unsigned short* a1p = a0p + (size_t)128 * K;
  const unsigned short* b0p = W + (size_t)(n0 + sr) * K + sc;
  const unsigned short* b1p = b0p + (size_t)128 * K;
  const int wl = wv * 512;  // wave-uniform LDS base (ushorts) within a half

  // read addressing: XOR term identical for all frags of this thread
  const int x = ((l15 >> 1) & 3) << 3;
  const int aoff = (wmL + l15) * 32 + ((kg * 8) ^ x);
  const int boff = (wnL + l15) * 32 + ((kg * 8) ^ x);

  f32x4 acc[8][4];
#pragma unroll
  for (int i = 0; i < 8; ++i)
#pragma unroll
    for (int j = 0; j < 4; ++j) acc[i][j] = (f32x4){0.f, 0.f, 0.f, 0.f};

  // prologue: fill steps 0,1,2 (12 loads); wait so step 0 is resident
  STAGE_A(0); STAGE_B(0); STAGE_A(1); STAGE_B(1); STAGE_A(2); STAGE_B(2);
  STEP_WAIT("vmcnt(8)")

  for (int s = 0; s < 29; ++s) {
    GEMM_STEP(s, 1);
    STEP_WAIT("vmcnt(8)")
  }
  GEMM_STEP(29, 0);
  STEP_WAIT("vmcnt(4)")
  GEMM_STEP(30, 0);
  STEP_WAIT("vmcnt(0)")
  GEMM_STEP(31, 0);

#pragma unroll
  for (int mi = 0; mi < 8; ++mi) {
#pragma unroll
    for (int ni = 0; ni < 4; ++ni) {
      int col = n0 + wnL + ni * 16 + l15;
      float bcol = bias[col];
#pragma unroll
      for (int r = 0; r < 4; ++r) {
        int row = m0 + wmL + mi * 16 + kg * 4 + r;
        float v = acc[mi][ni][r] + bcol;
        if constexpr (QSCALE) v *= 0.125f;
        if constexpr (OUT_F32)
          ((float*)Cv)[(size_t)row * N + col] = v;
        else
          ((unsigned short*)Cv)[(size_t)row * N + col] = f2b(v);
      }
    }
  }
}

// ---------------------------------------------------------------------------
// MFMA attention per (b,h). 8 waves x 32 t-rows (2 strips of 16).
// S^T = K·Q^T via mfma (lane: t=l15, s=g*4+r); online softmax in f32;
// P^T staged through a PRIVATE per-wave LDS tile (no shfl routing, no asm);
// O^T = V^T·P^T via mfma, V^T stored chunk-XOR-swizzled in LDS.
// Prefix (P=16, zero-padded to 32) reuses the same P-tile path.
// combined = attn + g1[t>>2]*bw[b]*attn_pre   (uses g0+g1==1).
// Q is pre-scaled by 0.125 in the q-projection GEMM.
// ---------------------------------------------------------------------------
__global__ __launch_bounds__(512) void attn_kernel(
    const unsigned short* __restrict__ qb, const unsigned short* __restrict__ kb,
    const unsigned short* __restrict__ vb, const float* __restrict__ prefix,
    const float* __restrict__ bw, const float* __restrict__ g1,
    unsigned short* __restrict__ comb) {
  const int b = blockIdx.x, h = blockIdx.y;
  __shared__ __attribute__((aligned(16))) unsigned short Kl[256][64];    // 32 KB, chunk-XOR
  __shared__ __attribute__((aligned(16))) unsigned short Vt[64 * 256];   // 32 KB, V^T chunk-XOR
  __shared__ __attribute__((aligned(16))) unsigned short PKl[16][64];    // 2 KB, chunk-XOR
  __shared__ __attribute__((aligned(16))) unsigned short PVt[64][32];    // 4 KB
  __shared__ __attribute__((aligned(16))) unsigned short Plds[8][16][40];// 10 KB, per-wave P
  unsigned short* Cb = &Kl[0][0];  // output bounce overlays Kl (exactly 16384 ushorts)
  const int tid = threadIdx.x;

  // ---- staging ----
#pragma unroll
  for (int it = 0; it < 4; ++it) {
    int cid = tid + it * 512;
    int j = cid >> 3, c = cid & 7;  // j = s row, c = d-chunk
    size_t gro = (size_t)(j * BSZ + b) * EMB + h * HD + c * 8;
    *(ushort8*)&Kl[j][((c ^ (j & 7)) << 3)] = *(const ushort8*)(kb + gro);
    ushort8 vv = *(const ushort8*)(vb + gro);
#pragma unroll
    for (int i = 0; i < 8; ++i)  // V^T: element (d=c*8+i, s=j) at [d][((s>>3)^(d&7))<<3 | (s&7)]
      Vt[(c * 8 + i) * 256 + (((j >> 3) ^ i) << 3) + (j & 7)] = vv[i];
  }
  if (tid < 256) {
    int arr = tid >> 7, cid = tid & 127;
    int sp = cid >> 3, c = cid & 7;
    const float* src = prefix + ((size_t)(b * 2 + arr) * PP + sp) * EMB + h * HD + c * 8;
    float4v v0 = *(const float4v*)src;
    float4v v1 = *(const float4v*)(src + 4);
    if (arr == 0) {
      ushort8 o = {f2b(v0[0]), f2b(v0[1]), f2b(v0[2]), f2b(v0[3]),
                   f2b(v1[0]), f2b(v1[1]), f2b(v1[2]), f2b(v1[3])};
      *(ushort8*)&PKl[sp][((c ^ (sp & 7)) << 3)] = o;
    } else {
#pragma unroll
      for (int i = 0; i < 8; ++i)
        PVt[c * 8 + i][sp] = f2b(i < 4 ? v0[i] : v1[i - 4]);
    }
  } else if (tid < 384) {
    int cid = tid - 256;
    *(ushort8*)&PVt[cid >> 1][16 + (cid & 1) * 8] = (ushort8){0, 0, 0, 0, 0, 0, 0, 0};
  }
  __syncthreads();

  const int wv = tid >> 6, lane = tid & 63;
  const int l15 = lane & 15, g = lane >> 4;
  const int swl = l15 & 7;
  const float bwb = bw[b];
  unsigned short(&Pw)[16][40] = Plds[wv];
  f32x4 Oacc[2][4];

#pragma unroll
  for (int sI = 0; sI < 2; ++sI) {
    const int tg = wv * 32 + sI * 16 + l15;
    const size_t qoff = (size_t)(tg * BSZ + b) * EMB + h * HD;
    bf16x8 qf0 = *(const bf16x8*)(qb + qoff + g * 8);
    bf16x8 qf1 = *(const bf16x8*)(qb + qoff + 32 + g * 8);
    f32x4 O[4];
#pragma unroll
    for (int dt = 0; dt < 4; ++dt) O[dt] = (f32x4){0.f, 0.f, 0.f, 0.f};
    float m = -3.0e38f, l = 0.f;

#pragma unroll
    for (int ch = 0; ch < 8; ++ch) {  // 32 s per chunk
      const int rA = ch * 32 + l15, rB = rA + 16;
      bf16x8 ka0 = *(const bf16x8*)&Kl[rA][((g ^ swl) << 3)];
      bf16x8 ka1 = *(const bf16x8*)&Kl[rA][(((4 + g) ^ swl) << 3)];
      bf16x8 kb0 = *(const bf16x8*)&Kl[rB][((g ^ swl) << 3)];
      bf16x8 kb1 = *(const bf16x8*)&Kl[rB][(((4 + g) ^ swl) << 3)];
      f32x4 sa = (f32x4){0.f, 0.f, 0.f, 0.f}, sb = sa;
      sa = mfma16(ka0, qf0, sa);
      sa = mfma16(ka1, qf1, sa);
      sb = mfma16(kb0, qf0, sb);
      sb = mfma16(kb1, qf1, sb);
      float mx = fmaxf(fmaxf(fmaxf(sa[0], sa[1]), fmaxf(sa[2], sa[3])),
                       fmaxf(fmaxf(sb[0], sb[1]), fmaxf(sb[2], sb[3])));
      mx = fmaxf(mx, __shfl_xor(mx, 16));
      mx = fmaxf(mx, __shfl_xor(mx, 32));
      float mn = fmaxf(m, mx);
      float f = __expf(m - mn);
      m = mn;
      float pA[4], pB[4];
#pragma unroll
      for (int r = 0; r < 4; ++r) {
        pA[r] = __expf(sa[r] - m);
        pB[r] = __expf(sb[r] - m);
      }
      uint2v wa = {pack2(pA[0], pA[1]), pack2(pA[2], pA[3])};
      uint2v wb2 = {pack2(pB[0], pB[1]), pack2(pB[2], pB[3])};
      *(uint2v*)&Pw[l15][g * 4] = wa;
      *(uint2v*)&Pw[l15][16 + g * 4] = wb2;
      float sloc = b2f((unsigned short)(wa[0] & 0xffff)) + b2f((unsigned short)(wa[0] >> 16)) +
                   b2f((unsigned short)(wa[1] & 0xffff)) + b2f((unsigned short)(wa[1] >> 16)) +
                   b2f((unsigned short)(wb2[0] & 0xffff)) + b2f((unsigned short)(wb2[0] >> 16)) +
                   b2f((unsigned short)(wb2[1] & 0xffff)) + b2f((unsigned short)(wb2[1] >> 16));
      l = l * f + sloc;
#pragma unroll
      for (int dt = 0; dt < 4; ++dt)
#pragma unroll
        for (int r = 0; r < 4; ++r) O[dt][r] *= f;
      bf16x8 pf = *(const bf16x8*)&Pw[l15][g * 8];
#pragma unroll
      for (int dt = 0; dt < 4; ++dt) {
        const int drow = dt * 16 + l15;
        bf16x8 vf = *(const bf16x8*)&Vt[drow * 256 + (((ch * 4 + g) ^ (drow & 7)) << 3)];
        O[dt] = mfma16(vf, pf, O[dt]);
      }
    }

    float lf = l;
    lf += __shfl_xor(lf, 16);
    lf += __shfl_xor(lf, 32);
    float inv = 1.0f / lf;
#pragma unroll
    for (int dt = 0; dt < 4; ++dt)
#pragma unroll
      for (int r = 0; r < 4; ++r) O[dt][r] *= inv;

    bf16x8 pk0 = *(const bf16x8*)&PKl[l15][((g ^ swl) << 3)];
    bf16x8 pk1 = *(const bf16x8*)&PKl[l15][(((4 + g) ^ swl) << 3)];
    f32x4 sp4 = (f32x4){0.f, 0.f, 0.f, 0.f};
    sp4 = mfma16(pk0, qf0, sp4);
    sp4 = mfma16(pk1, qf1, sp4);
    float pm = fmaxf(fmaxf(sp4[0], sp4[1]), fmaxf(sp4[2], sp4[3]));
    pm = fmaxf(pm, __shfl_xor(pm, 16));
    pm = fmaxf(pm, __shfl_xor(pm, 32));
    float pe[4], pl = 0.f;
#pragma unroll
    for (int r = 0; r < 4; ++r) {
      pe[r] = __expf(sp4[r] - pm);
      pl += pe[r];
    }
    pl += __shfl_xor(pl, 16);
    pl += __shfl_xor(pl, 32);
    float cpre = g1[tg >> 2] * bwb / pl;
#pragma unroll
    for (int r = 0; r < 4; ++r) pe[r] *= cpre;
    *(uint2v*)&Pw[l15][g * 4] = (uint2v){pack2(pe[0], pe[1]), pack2(pe[2], pe[3])};
    *(uint2v*)&Pw[l15][16 + g * 4] = (uint2v){0u, 0u};
    bf16x8 ppf = *(const bf16x8*)&Pw[l15][g * 8];
#pragma unroll
    for (int dt = 0; dt < 4; ++dt) {
      bf16x8 pvf = *(const bf16x8*)&PVt[dt * 16 + l15][g * 8];
      O[dt] = mfma16(pvf, ppf, O[dt]);
    }
#pragma unroll
    for (int dt = 0; dt < 4; ++dt) Oacc[sI][dt] = O[dt];
  }

  __syncthreads();  // all waves done reading Kl before bounce overlays it
#pragma unroll
  for (int sI = 0; sI < 2; ++sI) {
    int t = wv * 32 + sI * 16 + l15;
#pragma unroll
    for (int dt = 0; dt < 4; ++dt) {
#pragma unroll
      for (int u = 0; u < 2; ++u) {
        unsigned int pw = pack2(Oacc[sI][dt][2 * u], Oacc[sI][dt][2 * u + 1]);
        int d = dt * 16 + g * 4 + 2 * u;
        *(unsigned int*)&Cb[t * 64 + (((d >> 3) ^ (t & 7)) << 3) + (d & 7)] = pw;
      }
    }
  }
  __syncthreads();
#pragma unroll
  for (int it = 0; it < 4; ++it) {
    int cid = tid + it * 512;
    int j = cid >> 3, c = cid & 7;
    ushort8 row = *(const ushort8*)&Cb[j * 64 + ((c ^ (j & 7)) << 3)];
    *(ushort8*)(comb + (size_t)(j * BSZ + b) * EMB + h * HD + c * 8) = row;
  }
}

// ---------------------------------------------------------------------------
extern "C" void kernel_launch(void* const* d_in, const int* in_sizes, int n_in,
                              void* d_out, int out_size, void* d_ws, size_t ws_size,
                              hipStream_t stream) {
  const float* query = (const float*)d_in[1];
  const float* key = (const float*)d_in[2];
  const float* value = (const float*)d_in[3];
  const float* prefix = (const float*)d_in[4];
  const float* bw = (const float*)d_in[5];
  const float* feat = (const float*)d_in[6];
  const float* noise = (const float*)d_in[7];
  const float* ipw = (const float*)d_in[8];
  const float* ipb = (const float*)d_in[9];
  const float* outw = (const float*)d_in[10];
  const float* outb = (const float*)d_in[11];
  const float* gw = (const float*)d_in[12];
  const float* gb = (const float*)d_in[13];
  float* out = (float*)d_out;

  char* ws = (char*)d_ws;
  const size_t MATB = (size_t)16384 * 1024;  // elements per [16384,1024] matrix
  unsigned short* qb = (unsigned short*)ws;
  unsigned short* kb = qb + MATB;
  unsigned short* vb = kb + MATB;
  unsigned short* cb = vb + MATB;            // attn output; also A-cast scratch
  unsigned short* wip = cb + MATB;           // bf16 in_proj_w [3072,1024]
  unsigned short* wo = wip + (size_t)3072 * 1024;  // bf16 out_w [1024,1024]
  float* g1 = (float*)(wo + (size_t)1024 * 1024);

  gate_kernel<<<64, 64, 0, stream>>>(feat, gw, gb, noise, g1);

  // one-time weight casts (cheap: 12.6 MB + 4.2 MB read)
  cast_bf16_kernel<<<1536, 256, 0, stream>>>(ipw, wip, 3072 * 1024 / 8);
  cast_bf16_kernel<<<512, 256, 0, stream>>>(outw, wo, 1024 * 1024 / 8);

  const int N8 = (int)(MATB / 8);
  // q projection (cb used as bf16-A scratch before attn overwrites it)
  cast_bf16_kernel<<<2048, 256, 0, stream>>>(query, cb, N8);
  gemm256_kernel<0, 1><<<256, 512, 0, stream>>>(cb, wip, ipb, qb);
  // k projection
  cast_bf16_kernel<<<2048, 256, 0, stream>>>(key, cb, N8);
  gemm256_kernel<0, 0><<<256, 512, 0, stream>>>(cb, wip + (size_t)1024 * 1024, ipb + 1024, kb);
  // v projection
  cast_bf16_kernel<<<2048, 256, 0, stream>>>(value, cb, N8);
  gemm256_kernel<0, 0><<<256, 512, 0, stream>>>(cb, wip + (size_t)2048 * 1024, ipb + 2048, vb);

  attn_kernel<<<dim3(64, 16), 512, 0, stream>>>(qb, kb, vb, prefix, bw, g1, cb);

  gemm256_kernel<1, 0><<<256, 512, 0, stream>>>(cb, wo, outb, out);
}

// Round 3
// 292.449 us; speedup vs baseline: 1.5930x; 1.0097x over previous
//
#include <hip/hip_runtime.h>

typedef __attribute__((ext_vector_type(8))) short bf16x8;
typedef __attribute__((ext_vector_type(4))) float f32x4;
typedef __attribute__((ext_vector_type(8))) unsigned short ushort8;
typedef __attribute__((ext_vector_type(4))) unsigned short ushort4v;
typedef __attribute__((ext_vector_type(4))) float float4v;
typedef __attribute__((ext_vector_type(2))) unsigned int uint2v;

#define TGT 256
#define BSZ 64
#define EMB 1024
#define NH 16
#define HD 64
#define PP 16

__device__ __forceinline__ float b2f(unsigned short u) {
  return __builtin_bit_cast(float, ((unsigned int)u) << 16);
}
__device__ __forceinline__ unsigned short f2b(float f) {
  unsigned int u = __builtin_bit_cast(unsigned int, f);
  u += 0x7fffu + ((u >> 16) & 1u);  // RNE; no NaNs in this workload
  return (unsigned short)(u >> 16);
}
__device__ __forceinline__ unsigned int pack2(float lo, float hi) {
  return (unsigned int)f2b(lo) | ((unsigned int)f2b(hi) << 16);
}
__device__ __forceinline__ f32x4 mfma16(bf16x8 a, bf16x8 b, f32x4 c) {
  return __builtin_amdgcn_mfma_f32_16x16x32_bf16(a, b, c, 0, 0, 0);
}
// async global->LDS, 16B per lane; LDS dest is wave-uniform base + lane*16
__device__ __forceinline__ void gl_lds16(const unsigned short* g, unsigned short* l) {
  __builtin_amdgcn_global_load_lds(
      (const __attribute__((address_space(1))) unsigned int*)g,
      (__attribute__((address_space(3))) unsigned int*)l, 16, 0, 0);
}

// ---------------------------------------------------------------------------
// Gate: g1[b] = softmax((feat[b]@gw.T + gb + noise[b]) / 3)[1]
// ---------------------------------------------------------------------------
__global__ __launch_bounds__(64) void gate_kernel(
    const float* __restrict__ feat, const float* __restrict__ gw,
    const float* __restrict__ gb, const float* __restrict__ noise,
    float* __restrict__ g1) {
  const int b = blockIdx.x, lane = threadIdx.x;
  float a0 = 0.f, a1 = 0.f;
  for (int i = lane; i < 512; i += 64) {
    float f = feat[b * 512 + i];
    a0 += f * gw[i];
    a1 += f * gw[512 + i];
  }
#pragma unroll
  for (int off = 32; off >= 1; off >>= 1) {
    a0 += __shfl_xor(a0, off);
    a1 += __shfl_xor(a1, off);
  }
  if (lane == 0) {
    float l0 = (a0 + gb[0] + noise[b * 2 + 0]) * (1.0f / 3.0f);
    float l1 = (a1 + gb[1] + noise[b * 2 + 1]) * (1.0f / 3.0f);
    float mm = fmaxf(l0, l1);
    float e0 = __expf(l0 - mm), e1 = __expf(l1 - mm);
    g1[b] = e1 / (e0 + e1);
  }
}

// ---------------------------------------------------------------------------
// f32 -> bf16 cast, 8 elems/thread, grid-stride
// ---------------------------------------------------------------------------
__global__ __launch_bounds__(256) void cast_bf16_kernel(
    const float* __restrict__ in, unsigned short* __restrict__ out, int n8) {
  int i = blockIdx.x * blockDim.x + threadIdx.x;
  const int stride = gridDim.x * blockDim.x;
  for (; i < n8; i += stride) {
    const float4v* p = (const float4v*)(in + (size_t)i * 8);
    float4v v0 = p[0], v1 = p[1];
    ushort8 o = {f2b(v0[0]), f2b(v0[1]), f2b(v0[2]), f2b(v0[3]),
                 f2b(v1[0]), f2b(v1[1]), f2b(v1[2]), f2b(v1[3])};
    *(ushort8*)(out + (size_t)i * 8) = o;
  }
}

// ---------------------------------------------------------------------------
// bf16 GEMM: C[16384,1024] = A[16384,1024] @ W[1024,1024]^T + bias
// 256x256 tile, 8 waves (2Mx4N, each owns 128x64), BK=32, K=1024 -> 32 steps.
// Phase-interleaved schedule with COUNTED vmcnt (T3+T4), LDS XOR swizzle (T2),
// setprio around MFMA clusters (T5), XCD-chunked block swizzle (T1).
// Ring of 4 K-step slots; prefetch lead 3; steady wait vmcnt(8). See R2 notes.
// ---------------------------------------------------------------------------
#define STAGE_A(s)                                       \
  {                                                      \
    int k0s = (s) * 32;                                  \
    unsigned short* d = &As[(s) & 3][wl];                \
    gl_lds16(a0p + k0s, d);                              \
    gl_lds16(a1p + k0s, d + 4096);                       \
  }
#define STAGE_B(s)                                       \
  {                                                      \
    int k0s = (s) * 32;                                  \
    unsigned short* d = &Bs[(s) & 3][wl];                \
    gl_lds16(b0p + k0s, d);                              \
    gl_lds16(b1p + k0s, d + 4096);                       \
  }
#define GEMM_STEP(s, DO_STAGE)                                        \
  {                                                                   \
    const unsigned short* Ab = &As[(s) & 3][0];                       \
    const unsigned short* Bb = &Bs[(s) & 3][0];                       \
    bf16x8 af[8], bfr[4];                                             \
    _Pragma("unroll") for (int mi = 0; mi < 8; ++mi)                  \
        af[mi] = *(const bf16x8*)&Ab[aoff + mi * 512];                \
    _Pragma("unroll") for (int ni = 0; ni < 2; ++ni)                  \
        bfr[ni] = *(const bf16x8*)&Bb[boff + ni * 512];               \
    if (DO_STAGE) STAGE_A((s) + 3);                                   \
    __builtin_amdgcn_s_barrier();                                     \
    __builtin_amdgcn_s_setprio(1);                                    \
    _Pragma("unroll") for (int mi = 0; mi < 8; ++mi) {                \
      acc[mi][0] = mfma16(af[mi], bfr[0], acc[mi][0]);                \
      acc[mi][1] = mfma16(af[mi], bfr[1], acc[mi][1]);                \
    }                                                                 \
    __builtin_amdgcn_s_setprio(0);                                    \
    __builtin_amdgcn_s_barrier();                                     \
    _Pragma("unroll") for (int ni = 2; ni < 4; ++ni)                  \
        bfr[ni] = *(const bf16x8*)&Bb[boff + ni * 512];               \
    if (DO_STAGE) STAGE_B((s) + 3);                                   \
    __builtin_amdgcn_s_barrier();                                     \
    __builtin_amdgcn_s_setprio(1);                                    \
    _Pragma("unroll") for (int mi = 0; mi < 8; ++mi) {                \
      acc[mi][2] = mfma16(af[mi], bfr[2], acc[mi][2]);                \
      acc[mi][3] = mfma16(af[mi], bfr[3], acc[mi][3]);                \
    }                                                                 \
    __builtin_amdgcn_s_setprio(0);                                    \
  }
#define STEP_WAIT(cntstr)                                \
  asm volatile("s_waitcnt " cntstr ::: "memory");        \
  __builtin_amdgcn_sched_barrier(0);                     \
  __builtin_amdgcn_s_barrier();

template <int OUT_F32, int QSCALE>
__global__ __launch_bounds__(512, 2) void gemm256_kernel(
    const unsigned short* __restrict__ A, const unsigned short* __restrict__ W,
    const float* __restrict__ bias, void* __restrict__ Cv) {
  constexpr int K = 1024, N = 1024;
  __shared__ __attribute__((aligned(16))) unsigned short As[4][8192];  // 64 KB
  __shared__ __attribute__((aligned(16))) unsigned short Bs[4][8192];  // 64 KB
  const int tid = threadIdx.x;
  const int wv = tid >> 6, lane = tid & 63;
  const int l15 = lane & 15, kg = lane >> 4;
  const int bid = blockIdx.x;
  const int cpx = gridDim.x >> 3;
  const int wg = (bid & 7) * cpx + (bid >> 3);
  const int m0 = (wg >> 2) * 256, n0 = (wg & 3) * 256;
  const int wmL = (wv >> 2) * 128, wnL = (wv & 3) * 64;

  const int sr = wv * 16 + (lane >> 2);
  const int sc = ((lane & 3) * 8) ^ (((sr >> 1) & 3) << 3);  // pre-swizzled src col
  const unsigned short* a0p = A + (size_t)(m0 + sr) * K + sc;
  const unsigned short* a1p = a0p + (size_t)128 * K;
  const unsigned short* b0p = W + (size_t)(n0 + sr) * K + sc;
  const unsigned short* b1p = b0p + (size_t)128 * K;
  const int wl = wv * 512;

  const int x = ((l15 >> 1) & 3) << 3;
  const int aoff = (wmL + l15) * 32 + ((kg * 8) ^ x);
  const int boff = (wnL + l15) * 32 + ((kg * 8) ^ x);

  f32x4 acc[8][4];
#pragma unroll
  for (int i = 0; i < 8; ++i)
#pragma unroll
    for (int j = 0; j < 4; ++j) acc[i][j] = (f32x4){0.f, 0.f, 0.f, 0.f};

  STAGE_A(0); STAGE_B(0); STAGE_A(1); STAGE_B(1); STAGE_A(2); STAGE_B(2);
  STEP_WAIT("vmcnt(8)")

  for (int s = 0; s < 29; ++s) {
    GEMM_STEP(s, 1);
    STEP_WAIT("vmcnt(8)")
  }
  GEMM_STEP(29, 0);
  STEP_WAIT("vmcnt(4)")
  GEMM_STEP(30, 0);
  STEP_WAIT("vmcnt(0)")
  GEMM_STEP(31, 0);

#pragma unroll
  for (int mi = 0; mi < 8; ++mi) {
#pragma unroll
    for (int ni = 0; ni < 4; ++ni) {
      int col = n0 + wnL + ni * 16 + l15;
      float bcol = bias[col];
#pragma unroll
      for (int r = 0; r < 4; ++r) {
        int row = m0 + wmL + mi * 16 + kg * 4 + r;
        float v = acc[mi][ni][r] + bcol;
        if constexpr (QSCALE) v *= 0.125f;
        if constexpr (OUT_F32)
          ((float*)Cv)[(size_t)row * N + col] = v;
        else
          ((unsigned short*)Cv)[(size_t)row * N + col] = f2b(v);
      }
    }
  }
}

// ---------------------------------------------------------------------------
// MFMA attention per (b,h). 8 waves x 32 t-rows, STRIP-MERGED:
// both 16-row strips processed together; K/V/prefix frags (which depend only
// on lane, not on t) are loaded ONCE and shared by both strips; the two
// softmax chains are independent -> 2x ILP at low occupancy.
// V^T layout: element (d,s) at d*256 + gran*8 + (s&7), gran = (s>>3)^(d&7)^(d>>3).
// The ^(d>>3) term makes the 8 c-lanes of a staging wave hit 8 distinct bank
// groups (was 16-way conflicted); reads stay 2-way (free).
// T13 defer-rescale: skip O-rescale when all rows' chunk max <= m+8.
// combined = attn + g1[t>>2]*bw[b]*attn_pre (uses g0+g1==1).
// Q pre-scaled by 0.125 in the q-projection GEMM.
// ---------------------------------------------------------------------------
__global__ __launch_bounds__(512) void attn_kernel(
    const unsigned short* __restrict__ qb, const unsigned short* __restrict__ kb,
    const unsigned short* __restrict__ vb, const float* __restrict__ prefix,
    const float* __restrict__ bw, const float* __restrict__ g1,
    unsigned short* __restrict__ comb) {
  const int b = blockIdx.x, h = blockIdx.y;
  __shared__ __attribute__((aligned(16))) unsigned short Kl[256][64];    // 32 KB, chunk-XOR
  __shared__ __attribute__((aligned(16))) unsigned short Vt[64 * 256];   // 32 KB, V^T swizzled
  __shared__ __attribute__((aligned(16))) unsigned short PKl[16][64];    // 2 KB, chunk-XOR
  __shared__ __attribute__((aligned(16))) unsigned short PVt[64][32];    // 4 KB
  __shared__ __attribute__((aligned(16))) unsigned short Plds[8][16][40];// 10 KB, per-wave P
  unsigned short* Cb = &Kl[0][0];  // output bounce overlays Kl (exactly 16384 ushorts)
  const int tid = threadIdx.x;

  // ---- staging ----
#pragma unroll
  for (int it = 0; it < 4; ++it) {
    int cid = tid + it * 512;
    int j = cid >> 3, c = cid & 7;  // j = s row, c = d-chunk
    size_t gro = (size_t)(j * BSZ + b) * EMB + h * HD + c * 8;
    *(ushort8*)&Kl[j][((c ^ (j & 7)) << 3)] = *(const ushort8*)(kb + gro);
    ushort8 vv = *(const ushort8*)(vb + gro);
#pragma unroll
    for (int i = 0; i < 8; ++i) {  // V^T: (d=c*8+i, s=j); gran = (s>>3)^(d&7)^(d>>3)
      int gran = (j >> 3) ^ i ^ c;
      Vt[(c * 8 + i) * 256 + gran * 8 + (j & 7)] = vv[i];
    }
  }
  if (tid < 256) {
    int arr = tid >> 7, cid = tid & 127;
    int sp = cid >> 3, c = cid & 7;
    const float* src = prefix + ((size_t)(b * 2 + arr) * PP + sp) * EMB + h * HD + c * 8;
    float4v v0 = *(const float4v*)src;
    float4v v1 = *(const float4v*)(src + 4);
    if (arr == 0) {
      ushort8 o = {f2b(v0[0]), f2b(v0[1]), f2b(v0[2]), f2b(v0[3]),
                   f2b(v1[0]), f2b(v1[1]), f2b(v1[2]), f2b(v1[3])};
      *(ushort8*)&PKl[sp][((c ^ (sp & 7)) << 3)] = o;
    } else {
#pragma unroll
      for (int i = 0; i < 8; ++i)
        PVt[c * 8 + i][sp] = f2b(i < 4 ? v0[i] : v1[i - 4]);
    }
  } else if (tid < 384) {
    int cid = tid - 256;
    *(ushort8*)&PVt[cid >> 1][16 + (cid & 1) * 8] = (ushort8){0, 0, 0, 0, 0, 0, 0, 0};
  }
  __syncthreads();

  const int wv = tid >> 6, lane = tid & 63;
  const int l15 = lane & 15, g = lane >> 4;
  const int swl = l15 & 7;
  const float bwb = bw[b];
  unsigned short(&Pw)[16][40] = Plds[wv];

  const int t0 = wv * 32 + l15;  // strip-0 row; strip-1 = t0+16
  const size_t qo0 = (size_t)(t0 * BSZ + b) * EMB + h * HD;
  const size_t qo1 = (size_t)((t0 + 16) * BSZ + b) * EMB + h * HD;
  bf16x8 qf[2][2];
  qf[0][0] = *(const bf16x8*)(qb + qo0 + g * 8);
  qf[0][1] = *(const bf16x8*)(qb + qo0 + 32 + g * 8);
  qf[1][0] = *(const bf16x8*)(qb + qo1 + g * 8);
  qf[1][1] = *(const bf16x8*)(qb + qo1 + 32 + g * 8);

  f32x4 O[2][4];
#pragma unroll
  for (int st = 0; st < 2; ++st)
#pragma unroll
    for (int dt = 0; dt < 4; ++dt) O[st][dt] = (f32x4){0.f, 0.f, 0.f, 0.f};
  float m[2] = {-3.0e38f, -3.0e38f}, l[2] = {0.f, 0.f};

#pragma unroll
  for (int ch = 0; ch < 8; ++ch) {  // 32 s per chunk
    const int rA = ch * 32 + l15, rB = rA + 16;
    bf16x8 ka0 = *(const bf16x8*)&Kl[rA][((g ^ swl) << 3)];
    bf16x8 ka1 = *(const bf16x8*)&Kl[rA][(((4 + g) ^ swl) << 3)];
    bf16x8 kb0 = *(const bf16x8*)&Kl[rB][((g ^ swl) << 3)];
    bf16x8 kb1 = *(const bf16x8*)&Kl[rB][(((4 + g) ^ swl) << 3)];
    // QK^T for both strips with shared K frags (8 mfma)
    f32x4 s[2][2];
#pragma unroll
    for (int st = 0; st < 2; ++st) {
      s[st][0] = (f32x4){0.f, 0.f, 0.f, 0.f};
      s[st][1] = (f32x4){0.f, 0.f, 0.f, 0.f};
      s[st][0] = mfma16(ka0, qf[st][0], s[st][0]);
      s[st][0] = mfma16(ka1, qf[st][1], s[st][0]);
      s[st][1] = mfma16(kb0, qf[st][0], s[st][1]);
      s[st][1] = mfma16(kb1, qf[st][1], s[st][1]);
    }
    bf16x8 pf[2];
#pragma unroll
    for (int st = 0; st < 2; ++st) {
      f32x4 sa = s[st][0], sb = s[st][1];
      float mx = fmaxf(fmaxf(fmaxf(sa[0], sa[1]), fmaxf(sa[2], sa[3])),
                       fmaxf(fmaxf(sb[0], sb[1]), fmaxf(sb[2], sb[3])));
      mx = fmaxf(mx, __shfl_xor(mx, 16));
      mx = fmaxf(mx, __shfl_xor(mx, 32));
      // T13 defer-rescale: only rescale when some row grew by > 8
      if (__ballot(mx > m[st] + 8.0f) != 0ull) {
        float mn = fmaxf(m[st], mx);
        float f = __expf(m[st] - mn);
        m[st] = mn;
        l[st] *= f;
#pragma unroll
        for (int dt = 0; dt < 4; ++dt)
#pragma unroll
          for (int r = 0; r < 4; ++r) O[st][dt][r] *= f;
      }
      float pA[4], pB[4];
#pragma unroll
      for (int r = 0; r < 4; ++r) {
        pA[r] = __expf(sa[r] - m[st]);
        pB[r] = __expf(sb[r] - m[st]);
      }
      uint2v wa = {pack2(pA[0], pA[1]), pack2(pA[2], pA[3])};
      uint2v wb2 = {pack2(pB[0], pB[1]), pack2(pB[2], pB[3])};
      *(uint2v*)&Pw[l15][g * 4] = wa;
      *(uint2v*)&Pw[l15][16 + g * 4] = wb2;
      // l accumulates the ROUNDED p so normalization compensates quantization
      float sloc = b2f((unsigned short)(wa[0] & 0xffff)) + b2f((unsigned short)(wa[0] >> 16)) +
                   b2f((unsigned short)(wa[1] & 0xffff)) + b2f((unsigned short)(wa[1] >> 16)) +
                   b2f((unsigned short)(wb2[0] & 0xffff)) + b2f((unsigned short)(wb2[0] >> 16)) +
                   b2f((unsigned short)(wb2[1] & 0xffff)) + b2f((unsigned short)(wb2[1] >> 16));
      l[st] += sloc;
      // read own B-frag before next strip overwrites the tile (in-order DS)
      pf[st] = *(const bf16x8*)&Pw[l15][g * 8];
    }
    // PV for both strips with shared V frags (8 mfma)
#pragma unroll
    for (int dt = 0; dt < 4; ++dt) {
      const int drow = dt * 16 + l15;
      const int gran = (ch * 4 + g) ^ (drow & 7) ^ (drow >> 3);
      bf16x8 vf = *(const bf16x8*)&Vt[drow * 256 + gran * 8];
      O[0][dt] = mfma16(vf, pf[0], O[0][dt]);
      O[1][dt] = mfma16(vf, pf[1], O[1][dt]);
    }
  }

  // normalize main attention
#pragma unroll
  for (int st = 0; st < 2; ++st) {
    float lf = l[st];
    lf += __shfl_xor(lf, 16);
    lf += __shfl_xor(lf, 32);
    float inv = 1.0f / lf;
#pragma unroll
    for (int dt = 0; dt < 4; ++dt)
#pragma unroll
      for (int r = 0; r < 4; ++r) O[st][dt][r] *= inv;
  }

  // prefix attention (s=16 zero-padded to 32), scaled by g1*bw/sum
  {
    bf16x8 pk0 = *(const bf16x8*)&PKl[l15][((g ^ swl) << 3)];
    bf16x8 pk1 = *(const bf16x8*)&PKl[l15][(((4 + g) ^ swl) << 3)];
    bf16x8 ppf[2];
#pragma unroll
    for (int st = 0; st < 2; ++st) {
      f32x4 sp4 = (f32x4){0.f, 0.f, 0.f, 0.f};
      sp4 = mfma16(pk0, qf[st][0], sp4);
      sp4 = mfma16(pk1, qf[st][1], sp4);
      float pm = fmaxf(fmaxf(sp4[0], sp4[1]), fmaxf(sp4[2], sp4[3]));
      pm = fmaxf(pm, __shfl_xor(pm, 16));
      pm = fmaxf(pm, __shfl_xor(pm, 32));
      float pe[4], pl = 0.f;
#pragma unroll
      for (int r = 0; r < 4; ++r) {
        pe[r] = __expf(sp4[r] - pm);
        pl += pe[r];
      }
      pl += __shfl_xor(pl, 16);
      pl += __shfl_xor(pl, 32);
      float cpre = g1[(t0 + 16 * st) >> 2] * bwb / pl;
#pragma unroll
      for (int r = 0; r < 4; ++r) pe[r] *= cpre;
      *(uint2v*)&Pw[l15][g * 4] = (uint2v){pack2(pe[0], pe[1]), pack2(pe[2], pe[3])};
      *(uint2v*)&Pw[l15][16 + g * 4] = (uint2v){0u, 0u};
      ppf[st] = *(const bf16x8*)&Pw[l15][g * 8];
    }
#pragma unroll
    for (int dt = 0; dt < 4; ++dt) {
      bf16x8 pvf = *(const bf16x8*)&PVt[dt * 16 + l15][g * 8];
      O[0][dt] = mfma16(pvf, ppf[0], O[0][dt]);
      O[1][dt] = mfma16(pvf, ppf[1], O[1][dt]);
    }
  }

  __syncthreads();  // all waves done reading Kl before bounce overlays it
#pragma unroll
  for (int st = 0; st < 2; ++st) {
    int t = wv * 32 + st * 16 + l15;
#pragma unroll
    for (int dt = 0; dt < 4; ++dt) {
#pragma unroll
      for (int u = 0; u < 2; ++u) {
        unsigned int pw = pack2(O[st][dt][2 * u], O[st][dt][2 * u + 1]);
        int d = dt * 16 + g * 4 + 2 * u;
        *(unsigned int*)&Cb[t * 64 + (((d >> 3) ^ (t & 7)) << 3) + (d & 7)] = pw;
      }
    }
  }
  __syncthreads();
#pragma unroll
  for (int it = 0; it < 4; ++it) {
    int cid = tid + it * 512;
    int j = cid >> 3, c = cid & 7;
    ushort8 row = *(const ushort8*)&Cb[j * 64 + ((c ^ (j & 7)) << 3)];
    *(ushort8*)(comb + (size_t)(j * BSZ + b) * EMB + h * HD + c * 8) = row;
  }
}

// ---------------------------------------------------------------------------
extern "C" void kernel_launch(void* const* d_in, const int* in_sizes, int n_in,
                              void* d_out, int out_size, void* d_ws, size_t ws_size,
                              hipStream_t stream) {
  const float* query = (const float*)d_in[1];
  const float* key = (const float*)d_in[2];
  const float* value = (const float*)d_in[3];
  const float* prefix = (const float*)d_in[4];
  const float* bw = (const float*)d_in[5];
  const float* feat = (const float*)d_in[6];
  const float* noise = (const float*)d_in[7];
  const float* ipw = (const float*)d_in[8];
  const float* ipb = (const float*)d_in[9];
  const float* outw = (const float*)d_in[10];
  const float* outb = (const float*)d_in[11];
  const float* gw = (const float*)d_in[12];
  const float* gb = (const float*)d_in[13];
  float* out = (float*)d_out;

  char* ws = (char*)d_ws;
  const size_t MATB = (size_t)16384 * 1024;  // elements per [16384,1024] matrix
  unsigned short* qb = (unsigned short*)ws;
  unsigned short* kb = qb + MATB;
  unsigned short* vb = kb + MATB;
  unsigned short* cb = vb + MATB;            // attn output; also A-cast scratch
  unsigned short* wip = cb + MATB;           // bf16 in_proj_w [3072,1024]
  unsigned short* wo = wip + (size_t)3072 * 1024;  // bf16 out_w [1024,1024]
  float* g1 = (float*)(wo + (size_t)1024 * 1024);

  gate_kernel<<<64, 64, 0, stream>>>(feat, gw, gb, noise, g1);

  // one-time weight casts (cheap: 12.6 MB + 4.2 MB read)
  cast_bf16_kernel<<<1536, 256, 0, stream>>>(ipw, wip, 3072 * 1024 / 8);
  cast_bf16_kernel<<<512, 256, 0, stream>>>(outw, wo, 1024 * 1024 / 8);

  const int N8 = (int)(MATB / 8);
  // q projection (cb used as bf16-A scratch before attn overwrites it)
  cast_bf16_kernel<<<2048, 256, 0, stream>>>(query, cb, N8);
  gemm256_kernel<0, 1><<<256, 512, 0, stream>>>(cb, wip, ipb, qb);
  // k projection
  cast_bf16_kernel<<<2048, 256, 0, stream>>>(key, cb, N8);
  gemm256_kernel<0, 0><<<256, 512, 0, stream>>>(cb, wip + (size_t)1024 * 1024, ipb + 1024, kb);
  // v projection
  cast_bf16_kernel<<<2048, 256, 0, stream>>>(value, cb, N8);
  gemm256_kernel<0, 0><<<256, 512, 0, stream>>>(cb, wip + (size_t)2048 * 1024, ipb + 2048, vb);

  attn_kernel<<<dim3(64, 16), 512, 0, stream>>>(qb, kb, vb, prefix, bw, g1, cb);

  gemm256_kernel<1, 0><<<256, 512, 0, stream>>>(cb, wo, outb, out);
}

// Round 4
// 279.033 us; speedup vs baseline: 1.6696x; 1.0481x over previous
//
#include <hip/hip_runtime.h>

typedef __attribute__((ext_vector_type(8))) short bf16x8;
typedef __attribute__((ext_vector_type(4))) float f32x4;
typedef __attribute__((ext_vector_type(8))) unsigned short ushort8;
typedef __attribute__((ext_vector_type(4))) unsigned short ushort4v;
typedef __attribute__((ext_vector_type(4))) float float4v;
typedef __attribute__((ext_vector_type(2))) unsigned int uint2v;

#define TGT 256
#define BSZ 64
#define EMB 1024
#define NH 16
#define HD 64
#define PP 16

__device__ __forceinline__ float b2f(unsigned short u) {
  return __builtin_bit_cast(float, ((unsigned int)u) << 16);
}
__device__ __forceinline__ unsigned short f2b(float f) {
  unsigned int u = __builtin_bit_cast(unsigned int, f);
  u += 0x7fffu + ((u >> 16) & 1u);  // RNE; no NaNs in this workload
  return (unsigned short)(u >> 16);
}
__device__ __forceinline__ unsigned int pack2(float lo, float hi) {
  return (unsigned int)f2b(lo) | ((unsigned int)f2b(hi) << 16);
}
__device__ __forceinline__ f32x4 mfma16(bf16x8 a, bf16x8 b, f32x4 c) {
  return __builtin_amdgcn_mfma_f32_16x16x32_bf16(a, b, c, 0, 0, 0);
}
// async global->LDS, 16B per lane; LDS dest is wave-uniform base + lane*16
__device__ __forceinline__ void gl_lds16(const unsigned short* g, unsigned short* l) {
  __builtin_amdgcn_global_load_lds(
      (const __attribute__((address_space(1))) unsigned int*)g,
      (__attribute__((address_space(3))) unsigned int*)l, 16, 0, 0);
}

// ---------------------------------------------------------------------------
// Gate: g1[b] = softmax((feat[b]@gw.T + gb + noise[b]) / 3)[1]
// ---------------------------------------------------------------------------
__global__ __launch_bounds__(64) void gate_kernel(
    const float* __restrict__ feat, const float* __restrict__ gw,
    const float* __restrict__ gb, const float* __restrict__ noise,
    float* __restrict__ g1) {
  const int b = blockIdx.x, lane = threadIdx.x;
  float a0 = 0.f, a1 = 0.f;
  for (int i = lane; i < 512; i += 64) {
    float f = feat[b * 512 + i];
    a0 += f * gw[i];
    a1 += f * gw[512 + i];
  }
#pragma unroll
  for (int off = 32; off >= 1; off >>= 1) {
    a0 += __shfl_xor(a0, off);
    a1 += __shfl_xor(a1, off);
  }
  if (lane == 0) {
    float l0 = (a0 + gb[0] + noise[b * 2 + 0]) * (1.0f / 3.0f);
    float l1 = (a1 + gb[1] + noise[b * 2 + 1]) * (1.0f / 3.0f);
    float mm = fmaxf(l0, l1);
    float e0 = __expf(l0 - mm), e1 = __expf(l1 - mm);
    g1[b] = e1 / (e0 + e1);
  }
}

// ---------------------------------------------------------------------------
// f32 -> bf16 cast, 8 elems/thread, grid-stride
// ---------------------------------------------------------------------------
__global__ __launch_bounds__(256) void cast_bf16_kernel(
    const float* __restrict__ in, unsigned short* __restrict__ out, int n8) {
  int i = blockIdx.x * blockDim.x + threadIdx.x;
  const int stride = gridDim.x * blockDim.x;
  for (; i < n8; i += stride) {
    const float4v* p = (const float4v*)(in + (size_t)i * 8);
    float4v v0 = p[0], v1 = p[1];
    ushort8 o = {f2b(v0[0]), f2b(v0[1]), f2b(v0[2]), f2b(v0[3]),
                 f2b(v1[0]), f2b(v1[1]), f2b(v1[2]), f2b(v1[3])};
    *(ushort8*)(out + (size_t)i * 8) = o;
  }
}

// ---------------------------------------------------------------------------
// bf16 GEMM: C[16384,1024] = A[16384,1024] @ W[1024,1024]^T + bias
// 256x256 tile, 8 waves (2Mx4N, each owns 128x64), BK=32, K=1024 -> 32 steps.
// Phase-interleaved schedule with COUNTED vmcnt (T3+T4), LDS XOR swizzle (T2),
// setprio around MFMA clusters (T5), XCD-chunked block swizzle (T1).
// Ring of 4 K-step slots; prefetch lead 3; steady wait vmcnt(8).
//
// Layouts: A_BLOCKED reads A in head-blocked layout [(b*16+h)][t][d]
// (logical row m=(t*64+b), col k=(h*64+d)); OUT_F32==0 writes C head-blocked
// (the q/k/v projections feed the attn kernel); OUT_F32==1 writes row-major.
// ---------------------------------------------------------------------------
#define AOFF(s) (A_BLOCKED ? (((s) >> 1) * 16384 + ((s)&1) * 32) : (s)*32)
#define STAGE_A(s)                                       \
  {                                                      \
    const unsigned short* _ap = a0p + AOFF(s);           \
    unsigned short* d = &As[(s) & 3][wl];                \
    gl_lds16(_ap, d);                                    \
    gl_lds16(_ap + aD, d + 4096);                        \
  }
#define STAGE_B(s)                                       \
  {                                                      \
    int k0s = (s) * 32;                                  \
    unsigned short* d = &Bs[(s) & 3][wl];                \
    gl_lds16(b0p + k0s, d);                              \
    gl_lds16(b1p + k0s, d + 4096);                       \
  }
#define GEMM_STEP(s, DO_STAGE)                                        \
  {                                                                   \
    const unsigned short* Ab = &As[(s) & 3][0];                       \
    const unsigned short* Bb = &Bs[(s) & 3][0];                       \
    bf16x8 af[8], bfr[4];                                             \
    _Pragma("unroll") for (int mi = 0; mi < 8; ++mi)                  \
        af[mi] = *(const bf16x8*)&Ab[aoff + mi * 512];                \
    _Pragma("unroll") for (int ni = 0; ni < 2; ++ni)                  \
        bfr[ni] = *(const bf16x8*)&Bb[boff + ni * 512];               \
    if (DO_STAGE) STAGE_A((s) + 3);                                   \
    __builtin_amdgcn_s_barrier();                                     \
    __builtin_amdgcn_s_setprio(1);                                    \
    _Pragma("unroll") for (int mi = 0; mi < 8; ++mi) {                \
      acc[mi][0] = mfma16(af[mi], bfr[0], acc[mi][0]);                \
      acc[mi][1] = mfma16(af[mi], bfr[1], acc[mi][1]);                \
    }                                                                 \
    __builtin_amdgcn_s_setprio(0);                                    \
    __builtin_amdgcn_s_barrier();                                     \
    _Pragma("unroll") for (int ni = 2; ni < 4; ++ni)                  \
        bfr[ni] = *(const bf16x8*)&Bb[boff + ni * 512];               \
    if (DO_STAGE) STAGE_B((s) + 3);                                   \
    __builtin_amdgcn_s_barrier();                                     \
    __builtin_amdgcn_s_setprio(1);                                    \
    _Pragma("unroll") for (int mi = 0; mi < 8; ++mi) {                \
      acc[mi][2] = mfma16(af[mi], bfr[2], acc[mi][2]);                \
      acc[mi][3] = mfma16(af[mi], bfr[3], acc[mi][3]);                \
    }                                                                 \
    __builtin_amdgcn_s_setprio(0);                                    \
  }
#define STEP_WAIT(cntstr)                                \
  asm volatile("s_waitcnt " cntstr ::: "memory");        \
  __builtin_amdgcn_sched_barrier(0);                     \
  __builtin_amdgcn_s_barrier();

template <int OUT_F32, int QSCALE, int A_BLOCKED>
__global__ __launch_bounds__(512, 2) void gemm256_kernel(
    const unsigned short* __restrict__ A, const unsigned short* __restrict__ W,
    const float* __restrict__ bias, void* __restrict__ Cv) {
  constexpr int K = 1024, N = 1024;
  __shared__ __attribute__((aligned(16))) unsigned short As[4][8192];  // 64 KB
  __shared__ __attribute__((aligned(16))) unsigned short Bs[4][8192];  // 64 KB
  const int tid = threadIdx.x;
  const int wv = tid >> 6, lane = tid & 63;
  const int l15 = lane & 15, kg = lane >> 4;
  const int bid = blockIdx.x;
  const int cpx = gridDim.x >> 3;
  const int wg = (bid & 7) * cpx + (bid >> 3);
  const int m0 = (wg >> 2) * 256, n0 = (wg & 3) * 256;
  const int wmL = (wv >> 2) * 128, wnL = (wv & 3) * 64;

  const int sr = wv * 16 + (lane >> 2);
  const int sc = ((lane & 3) * 8) ^ (((sr >> 1) & 3) << 3);  // pre-swizzled src col
  const int srg = m0 + sr;
  const unsigned short* a0p;
  if constexpr (A_BLOCKED)
    a0p = A + (size_t)(srg & 63) * 262144 + (srg >> 6) * 64 + sc;
  else
    a0p = A + (size_t)srg * K + sc;
  const int aD = A_BLOCKED ? 128 : 128 * K;  // +128 logical rows
  const unsigned short* b0p = W + (size_t)(n0 + sr) * K + sc;
  const unsigned short* b1p = b0p + (size_t)128 * K;
  const int wl = wv * 512;

  const int x = ((l15 >> 1) & 3) << 3;
  const int aoff = (wmL + l15) * 32 + ((kg * 8) ^ x);
  const int boff = (wnL + l15) * 32 + ((kg * 8) ^ x);

  f32x4 acc[8][4];
#pragma unroll
  for (int i = 0; i < 8; ++i)
#pragma unroll
    for (int j = 0; j < 4; ++j) acc[i][j] = (f32x4){0.f, 0.f, 0.f, 0.f};

  STAGE_A(0); STAGE_B(0); STAGE_A(1); STAGE_B(1); STAGE_A(2); STAGE_B(2);
  STEP_WAIT("vmcnt(8)")

  for (int s = 0; s < 29; ++s) {
    GEMM_STEP(s, 1);
    STEP_WAIT("vmcnt(8)")
  }
  GEMM_STEP(29, 0);
  STEP_WAIT("vmcnt(4)")
  GEMM_STEP(30, 0);
  STEP_WAIT("vmcnt(0)")
  GEMM_STEP(31, 0);

#pragma unroll
  for (int mi = 0; mi < 8; ++mi) {
#pragma unroll
    for (int ni = 0; ni < 4; ++ni) {
      int col = n0 + wnL + ni * 16 + l15;
      float bcol = bias[col];
#pragma unroll
      for (int r = 0; r < 4; ++r) {
        int row = m0 + wmL + mi * 16 + kg * 4 + r;
        float v = acc[mi][ni][r] + bcol;
        if constexpr (QSCALE) v *= 0.125f;
        if constexpr (OUT_F32) {
          ((float*)Cv)[(size_t)row * N + col] = v;
        } else {
          // head-blocked store: [(b*16+h)][t][d]
          int t = row >> 6, bb = row & 63, hh = col >> 6, dd = col & 63;
          ((unsigned short*)Cv)[(size_t)((bb * 16 + hh) * 256 + t) * 64 + dd] = f2b(v);
        }
      }
    }
  }
}

// ---------------------------------------------------------------------------
// MFMA attention per (b,h). q/k/v/comb are HEAD-BLOCKED [(b*16+h)][t][d]:
// each (b,h) slab is a contiguous 32KB -> staging is fully coalesced streams
// (was: 128KB-strided 16B gathers, the latency bottleneck).
// 8 waves x 32 t-rows, strip-merged (shared K/V frags, 2 independent softmax
// chains). K staged via global_load_lds with pre-swizzled SOURCE (dest linear).
// V^T layout: (d,s) at d*256 + gran*8 + (s&7), gran=(s>>3)^(d&7)^(d>>3).
// T13 defer-rescale. combined = attn + g1[t>>2]*bw[b]*attn_pre (g0+g1==1).
// Q pre-scaled by 0.125 in the q-projection GEMM.
// ---------------------------------------------------------------------------
__global__ __launch_bounds__(512) void attn_kernel(
    const unsigned short* __restrict__ qb, const unsigned short* __restrict__ kb,
    const unsigned short* __restrict__ vb, const float* __restrict__ prefix,
    const float* __restrict__ bw, const float* __restrict__ g1,
    unsigned short* __restrict__ comb) {
  const int b = blockIdx.x, h = blockIdx.y;
  __shared__ __attribute__((aligned(16))) unsigned short Kl[256][64];    // 32 KB, chunk-XOR
  __shared__ __attribute__((aligned(16))) unsigned short Vt[64 * 256];   // 32 KB, V^T swizzled
  __shared__ __attribute__((aligned(16))) unsigned short PKl[16][64];    // 2 KB, chunk-XOR
  __shared__ __attribute__((aligned(16))) unsigned short PVt[64][32];    // 4 KB
  __shared__ __attribute__((aligned(16))) unsigned short Plds[8][16][40];// 10 KB, per-wave P
  unsigned short* Cb = &Kl[0][0];  // output bounce overlays Kl (exactly 16384 ushorts)
  const int tid = threadIdx.x;
  const int wv = tid >> 6, lane = tid & 63;
  const size_t slab = (size_t)(b * NH + h) * 16384;

  // ---- staging (coalesced slab reads) ----
#pragma unroll
  for (int it = 0; it < 4; ++it) {
    int cid = tid + it * 512;
    int j = cid >> 3, c = cid & 7;  // j = s row, c = d-chunk
    // K: gl_lds with pre-swizzled source; LDS dest linear = &Kl[j][c*8]
    gl_lds16(kb + slab + (size_t)j * 64 + ((c ^ (j & 7)) << 3),
             &Kl[0][0] + (size_t)(it * 512 + wv * 64) * 8);
    ushort8 vv = *(const ushort8*)(vb + slab + (size_t)j * 64 + (c << 3));
#pragma unroll
    for (int i = 0; i < 8; ++i) {  // V^T: (d=c*8+i, s=j); gran = (s>>3)^(d&7)^(d>>3)
      int gran = (j >> 3) ^ i ^ c;
      Vt[(c * 8 + i) * 256 + gran * 8 + (j & 7)] = vv[i];
    }
  }
  if (tid < 256) {
    int arr = tid >> 7, cid = tid & 127;
    int sp = cid >> 3, c = cid & 7;
    const float* src = prefix + ((size_t)(b * 2 + arr) * PP + sp) * EMB + h * HD + c * 8;
    float4v v0 = *(const float4v*)src;
    float4v v1 = *(const float4v*)(src + 4);
    if (arr == 0) {
      ushort8 o = {f2b(v0[0]), f2b(v0[1]), f2b(v0[2]), f2b(v0[3]),
                   f2b(v1[0]), f2b(v1[1]), f2b(v1[2]), f2b(v1[3])};
      *(ushort8*)&PKl[sp][((c ^ (sp & 7)) << 3)] = o;
    } else {
#pragma unroll
      for (int i = 0; i < 8; ++i)
        PVt[c * 8 + i][sp] = f2b(i < 4 ? v0[i] : v1[i - 4]);
    }
  } else if (tid < 384) {
    int cid = tid - 256;
    *(ushort8*)&PVt[cid >> 1][16 + (cid & 1) * 8] = (ushort8){0, 0, 0, 0, 0, 0, 0, 0};
  }
  __syncthreads();

  const int l15 = lane & 15, g = lane >> 4;
  const int swl = l15 & 7;
  const float bwb = bw[b];
  unsigned short(&Pw)[16][40] = Plds[wv];

  const int t0 = wv * 32 + l15;  // strip-0 row; strip-1 = t0+16
  const size_t qbase = slab + (size_t)t0 * 64;
  bf16x8 qf[2][2];
  qf[0][0] = *(const bf16x8*)(qb + qbase + g * 8);
  qf[0][1] = *(const bf16x8*)(qb + qbase + 32 + g * 8);
  qf[1][0] = *(const bf16x8*)(qb + qbase + 1024 + g * 8);        // t0+16
  qf[1][1] = *(const bf16x8*)(qb + qbase + 1024 + 32 + g * 8);

  f32x4 O[2][4];
#pragma unroll
  for (int st = 0; st < 2; ++st)
#pragma unroll
    for (int dt = 0; dt < 4; ++dt) O[st][dt] = (f32x4){0.f, 0.f, 0.f, 0.f};
  float m[2] = {-3.0e38f, -3.0e38f}, l[2] = {0.f, 0.f};

#pragma unroll
  for (int ch = 0; ch < 8; ++ch) {  // 32 s per chunk
    const int rA = ch * 32 + l15, rB = rA + 16;
    bf16x8 ka0 = *(const bf16x8*)&Kl[rA][((g ^ swl) << 3)];
    bf16x8 ka1 = *(const bf16x8*)&Kl[rA][(((4 + g) ^ swl) << 3)];
    bf16x8 kb0 = *(const bf16x8*)&Kl[rB][((g ^ swl) << 3)];
    bf16x8 kb1 = *(const bf16x8*)&Kl[rB][(((4 + g) ^ swl) << 3)];
    // QK^T for both strips with shared K frags (8 mfma)
    f32x4 s[2][2];
#pragma unroll
    for (int st = 0; st < 2; ++st) {
      s[st][0] = (f32x4){0.f, 0.f, 0.f, 0.f};
      s[st][1] = (f32x4){0.f, 0.f, 0.f, 0.f};
      s[st][0] = mfma16(ka0, qf[st][0], s[st][0]);
      s[st][0] = mfma16(ka1, qf[st][1], s[st][0]);
      s[st][1] = mfma16(kb0, qf[st][0], s[st][1]);
      s[st][1] = mfma16(kb1, qf[st][1], s[st][1]);
    }
    bf16x8 pf[2];
#pragma unroll
    for (int st = 0; st < 2; ++st) {
      f32x4 sa = s[st][0], sb = s[st][1];
      float mx = fmaxf(fmaxf(fmaxf(sa[0], sa[1]), fmaxf(sa[2], sa[3])),
                       fmaxf(fmaxf(sb[0], sb[1]), fmaxf(sb[2], sb[3])));
      mx = fmaxf(mx, __shfl_xor(mx, 16));
      mx = fmaxf(mx, __shfl_xor(mx, 32));
      // T13 defer-rescale: only rescale when some row grew by > 8
      if (__ballot(mx > m[st] + 8.0f) != 0ull) {
        float mn = fmaxf(m[st], mx);
        float f = __expf(m[st] - mn);
        m[st] = mn;
        l[st] *= f;
#pragma unroll
        for (int dt = 0; dt < 4; ++dt)
#pragma unroll
          for (int r = 0; r < 4; ++r) O[st][dt][r] *= f;
      }
      float pA[4], pB[4];
#pragma unroll
      for (int r = 0; r < 4; ++r) {
        pA[r] = __expf(sa[r] - m[st]);
        pB[r] = __expf(sb[r] - m[st]);
      }
      uint2v wa = {pack2(pA[0], pA[1]), pack2(pA[2], pA[3])};
      uint2v wb2 = {pack2(pB[0], pB[1]), pack2(pB[2], pB[3])};
      *(uint2v*)&Pw[l15][g * 4] = wa;
      *(uint2v*)&Pw[l15][16 + g * 4] = wb2;
      // l accumulates the ROUNDED p so normalization compensates quantization
      float sloc = b2f((unsigned short)(wa[0] & 0xffff)) + b2f((unsigned short)(wa[0] >> 16)) +
                   b2f((unsigned short)(wa[1] & 0xffff)) + b2f((unsigned short)(wa[1] >> 16)) +
                   b2f((unsigned short)(wb2[0] & 0xffff)) + b2f((unsigned short)(wb2[0] >> 16)) +
                   b2f((unsigned short)(wb2[1] & 0xffff)) + b2f((unsigned short)(wb2[1] >> 16));
      l[st] += sloc;
      // read own B-frag before next strip overwrites the tile (in-order DS)
      pf[st] = *(const bf16x8*)&Pw[l15][g * 8];
    }
    // PV for both strips with shared V frags (8 mfma)
#pragma unroll
    for (int dt = 0; dt < 4; ++dt) {
      const int drow = dt * 16 + l15;
      const int gran = (ch * 4 + g) ^ (drow & 7) ^ (drow >> 3);
      bf16x8 vf = *(const bf16x8*)&Vt[drow * 256 + gran * 8];
      O[0][dt] = mfma16(vf, pf[0], O[0][dt]);
      O[1][dt] = mfma16(vf, pf[1], O[1][dt]);
    }
  }

  // normalize main attention
#pragma unroll
  for (int st = 0; st < 2; ++st) {
    float lf = l[st];
    lf += __shfl_xor(lf, 16);
    lf += __shfl_xor(lf, 32);
    float inv = 1.0f / lf;
#pragma unroll
    for (int dt = 0; dt < 4; ++dt)
#pragma unroll
      for (int r = 0; r < 4; ++r) O[st][dt][r] *= inv;
  }

  // prefix attention (s=16 zero-padded to 32), scaled by g1*bw/sum
  {
    bf16x8 pk0 = *(const bf16x8*)&PKl[l15][((g ^ swl) << 3)];
    bf16x8 pk1 = *(const bf16x8*)&PKl[l15][(((4 + g) ^ swl) << 3)];
    bf16x8 ppf[2];
#pragma unroll
    for (int st = 0; st < 2; ++st) {
      f32x4 sp4 = (f32x4){0.f, 0.f, 0.f, 0.f};
      sp4 = mfma16(pk0, qf[st][0], sp4);
      sp4 = mfma16(pk1, qf[st][1], sp4);
      float pm = fmaxf(fmaxf(sp4[0], sp4[1]), fmaxf(sp4[2], sp4[3]));
      pm = fmaxf(pm, __shfl_xor(pm, 16));
      pm = fmaxf(pm, __shfl_xor(pm, 32));
      float pe[4], pl = 0.f;
#pragma unroll
      for (int r = 0; r < 4; ++r) {
        pe[r] = __expf(sp4[r] - pm);
        pl += pe[r];
      }
      pl += __shfl_xor(pl, 16);
      pl += __shfl_xor(pl, 32);
      float cpre = g1[(t0 + 16 * st) >> 2] * bwb / pl;
#pragma unroll
      for (int r = 0; r < 4; ++r) pe[r] *= cpre;
      *(uint2v*)&Pw[l15][g * 4] = (uint2v){pack2(pe[0], pe[1]), pack2(pe[2], pe[3])};
      *(uint2v*)&Pw[l15][16 + g * 4] = (uint2v){0u, 0u};
      ppf[st] = *(const bf16x8*)&Pw[l15][g * 8];
    }
#pragma unroll
    for (int dt = 0; dt < 4; ++dt) {
      bf16x8 pvf = *(const bf16x8*)&PVt[dt * 16 + l15][g * 8];
      O[0][dt] = mfma16(pvf, ppf[0], O[0][dt]);
      O[1][dt] = mfma16(pvf, ppf[1], O[1][dt]);
    }
  }

  __syncthreads();  // all waves done reading Kl before bounce overlays it
#pragma unroll
  for (int st = 0; st < 2; ++st) {
    int t = wv * 32 + st * 16 + l15;
#pragma unroll
    for (int dt = 0; dt < 4; ++dt) {
#pragma unroll
      for (int u = 0; u < 2; ++u) {
        unsigned int pw = pack2(O[st][dt][2 * u], O[st][dt][2 * u + 1]);
        int d = dt * 16 + g * 4 + 2 * u;
        *(unsigned int*)&Cb[t * 64 + (((d >> 3) ^ (t & 7)) << 3) + (d & 7)] = pw;
      }
    }
  }
  __syncthreads();
#pragma unroll
  for (int it = 0; it < 4; ++it) {
    int cid = tid + it * 512;
    int j = cid >> 3, c = cid & 7;
    ushort8 row = *(const ushort8*)&Cb[j * 64 + ((c ^ (j & 7)) << 3)];
    *(ushort8*)(comb + slab + (size_t)j * 64 + (c << 3)) = row;  // blocked store
  }
}

// ---------------------------------------------------------------------------
extern "C" void kernel_launch(void* const* d_in, const int* in_sizes, int n_in,
                              void* d_out, int out_size, void* d_ws, size_t ws_size,
                              hipStream_t stream) {
  const float* query = (const float*)d_in[1];
  const float* key = (const float*)d_in[2];
  const float* value = (const float*)d_in[3];
  const float* prefix = (const float*)d_in[4];
  const float* bw = (const float*)d_in[5];
  const float* feat = (const float*)d_in[6];
  const float* noise = (const float*)d_in[7];
  const float* ipw = (const float*)d_in[8];
  const float* ipb = (const float*)d_in[9];
  const float* outw = (const float*)d_in[10];
  const float* outb = (const float*)d_in[11];
  const float* gw = (const float*)d_in[12];
  const float* gb = (const float*)d_in[13];
  float* out = (float*)d_out;

  char* ws = (char*)d_ws;
  const size_t MATB = (size_t)16384 * 1024;  // elements per [16384,1024] matrix
  unsigned short* qb = (unsigned short*)ws;
  unsigned short* kb = qb + MATB;
  unsigned short* vb = kb + MATB;
  unsigned short* cb = vb + MATB;            // attn output; also A-cast scratch
  unsigned short* wip = cb + MATB;           // bf16 in_proj_w [3072,1024]
  unsigned short* wo = wip + (size_t)3072 * 1024;  // bf16 out_w [1024,1024]
  float* g1 = (float*)(wo + (size_t)1024 * 1024);

  gate_kernel<<<64, 64, 0, stream>>>(feat, gw, gb, noise, g1);

  // one-time weight casts (cheap: 12.6 MB + 4.2 MB read)
  cast_bf16_kernel<<<1536, 256, 0, stream>>>(ipw, wip, 3072 * 1024 / 8);
  cast_bf16_kernel<<<512, 256, 0, stream>>>(outw, wo, 1024 * 1024 / 8);

  const int N8 = (int)(MATB / 8);
  // q projection (cb used as bf16-A scratch before attn overwrites it)
  cast_bf16_kernel<<<2048, 256, 0, stream>>>(query, cb, N8);
  gemm256_kernel<0, 1, 0><<<256, 512, 0, stream>>>(cb, wip, ipb, qb);
  // k projection
  cast_bf16_kernel<<<2048, 256, 0, stream>>>(key, cb, N8);
  gemm256_kernel<0, 0, 0><<<256, 512, 0, stream>>>(cb, wip + (size_t)1024 * 1024, ipb + 1024, kb);
  // v projection
  cast_bf16_kernel<<<2048, 256, 0, stream>>>(value, cb, N8);
  gemm256_kernel<0, 0, 0><<<256, 512, 0, stream>>>(cb, wip + (size_t)2048 * 1024, ipb + 2048, vb);

  attn_kernel<<<dim3(64, 16), 512, 0, stream>>>(qb, kb, vb, prefix, bw, g1, cb);

  // out-projection reads head-blocked attn output
  gemm256_kernel<1, 0, 1><<<256, 512, 0, stream>>>(cb, wo, outb, out);
}